// Round 18
// baseline (250.846 us; speedup 1.0000x reference)
//
#include <hip/hip_runtime.h>

#define EMBED 1024
#define THREE_EMBED 3072
#define HEADS 16
#define HDIM 64
#define SEQ 2048
#define BATCH 2
#define MTOT 4096  // B*T

typedef short bf16x8 __attribute__((ext_vector_type(8)));
typedef float f32x4 __attribute__((ext_vector_type(4)));

#define MFMA16(a, b, c) __builtin_amdgcn_mfma_f32_16x16x32_bf16(a, b, c, 0, 0, 0)

__device__ __forceinline__ unsigned short f2bf(float f) {
  union { float f; unsigned int u; } v; v.f = f;
  unsigned int r = v.u + 0x7fffu + ((v.u >> 16) & 1u);
  return (unsigned short)(r >> 16);
}

__device__ __forceinline__ float bf2f(unsigned short u) {
  union { unsigned int u; float f; } v;
  v.u = (unsigned int)u << 16;
  return v.f;
}

// async 16B global->LDS. LDS dest is wave-uniform base + lane*16 (HW semantics).
__device__ __forceinline__ void gload_lds16(const unsigned short* g, unsigned short* l) {
  __builtin_amdgcn_global_load_lds(
      (const __attribute__((address_space(1))) void*)g,
      (__attribute__((address_space(3))) void*)l, 16, 0, 0);
}

__device__ __forceinline__ void wait_vm0_barrier() {
  asm volatile("s_waitcnt vmcnt(0)" ::: "memory");
  __builtin_amdgcn_s_barrier();
}

template <int N>
__device__ __forceinline__ void wait_vmcnt() {
  if constexpr (N == 0) asm volatile("s_waitcnt vmcnt(0)" ::: "memory");
  else if constexpr (N == 1) asm volatile("s_waitcnt vmcnt(1)" ::: "memory");
  else if constexpr (N == 2) asm volatile("s_waitcnt vmcnt(2)" ::: "memory");
  else if constexpr (N == 3) asm volatile("s_waitcnt vmcnt(3)" ::: "memory");
  else if constexpr (N == 4) asm volatile("s_waitcnt vmcnt(4)" ::: "memory");
  else if constexpr (N == 6) asm volatile("s_waitcnt vmcnt(6)" ::: "memory");
  else if constexpr (N == 8) asm volatile("s_waitcnt vmcnt(8)" ::: "memory");
}

// after-barrier LDS fence: wait all ds_reads issued pre-barrier, pin MFMA below (rule #18)
__device__ __forceinline__ void lds_fence() {
  asm volatile("s_waitcnt lgkmcnt(0)" ::: "memory");
  __builtin_amdgcn_sched_barrier(0);
}

// ---- merged weight transpose: fp32 [K][N] -> bf16 [N][K], 4 segments, 1 launch ----
__global__ __launch_bounds__(256) void k_transpose_all(
    const float* __restrict__ w_attn, const float* __restrict__ w_proj,
    const float* __restrict__ w_fc, const float* __restrict__ w_fc2,
    unsigned short* __restrict__ o_attn, unsigned short* __restrict__ o_proj,
    unsigned short* __restrict__ o_fc, unsigned short* __restrict__ o_fc2) {
  __shared__ float t[32][33];
  int bid = blockIdx.x;
  const float* in;
  unsigned short* out;
  int K, N, lid;
  if (bid < 3072) {
    in = w_attn; out = o_attn; K = 1024; N = 3072; lid = bid;
  } else if (bid < 4096) {
    in = w_proj; out = o_proj; K = 1024; N = 1024; lid = bid - 3072;
  } else if (bid < 8192) {
    in = w_fc; out = o_fc; K = 1024; N = 4096; lid = bid - 4096;
  } else {
    in = w_fc2; out = o_fc2; K = 4096; N = 1024; lid = bid - 8192;
  }
  int gx = N >> 5;
  int n0 = (lid % gx) * 32, k0 = (lid / gx) * 32;
  int tx = threadIdx.x & 31, ty = threadIdx.x >> 5;
#pragma unroll
  for (int i = 0; i < 32; i += 8)
    t[ty + i][tx] = in[(size_t)(k0 + ty + i) * N + n0 + tx];
  __syncthreads();
#pragma unroll
  for (int i = 0; i < 32; i += 8)
    out[(size_t)(n0 + ty + i) * K + k0 + tx] = f2bf(t[tx][ty + i]);
}

// ---------------- V transpose: qkv V-part -> Vt[bh][64][2048] bf16 ----------------
__global__ __launch_bounds__(256) void k_transpose_v(
    const unsigned short* __restrict__ qkv, unsigned short* __restrict__ Vt) {
  __shared__ unsigned short t[32][33];
  int tx = threadIdx.x & 31, ty = threadIdx.x >> 5;  // 32 x 8
  int t0 = blockIdx.x * 32;
  int d0 = (blockIdx.y & 1) * 32;
  int bh = blockIdx.y >> 1;
  int b = bh >> 4, h = bh & 15;
  const unsigned short* src = qkv + (size_t)b * SEQ * THREE_EMBED + 2 * EMBED + h * HDIM;
#pragma unroll
  for (int i = 0; i < 32; i += 8)
    t[ty + i][tx] = src[(size_t)(t0 + ty + i) * THREE_EMBED + d0 + tx];
  __syncthreads();
  unsigned short* dst = Vt + (size_t)bh * HDIM * SEQ;
#pragma unroll
  for (int i = 0; i < 32; i += 8)
    dst[(size_t)(d0 + ty + i) * SEQ + t0 + tx] = t[tx][ty + i];
}

// ---------------- layernorm fp32 [4096][1024] -> bf16 ----------------
__global__ __launch_bounds__(256) void k_layernorm(
    const float* __restrict__ x, const float* __restrict__ g,
    const float* __restrict__ b, unsigned short* __restrict__ out) {
  int row = blockIdx.x;
  int tid = threadIdx.x;
  const float4 xv = *(const float4*)(x + (size_t)row * EMBED + tid * 4);
  float s = xv.x + xv.y + xv.z + xv.w;
  float sq = xv.x * xv.x + xv.y * xv.y + xv.z * xv.z + xv.w * xv.w;
#pragma unroll
  for (int off = 1; off < 64; off <<= 1) {
    s += __shfl_xor(s, off);
    sq += __shfl_xor(sq, off);
  }
  __shared__ float red[8];
  int w = tid >> 6;
  if ((tid & 63) == 0) { red[w] = s; red[4 + w] = sq; }
  __syncthreads();
  s = red[0] + red[1] + red[2] + red[3];
  sq = red[4] + red[5] + red[6] + red[7];
  float mu = s * (1.0f / EMBED);
  float var = sq * (1.0f / EMBED) - mu * mu;
  float rs = rsqrtf(var + 1e-5f);
  float xs[4] = {xv.x, xv.y, xv.z, xv.w};
  unsigned short o[4];
#pragma unroll
  for (int c = 0; c < 4; c++) {
    int col = tid * 4 + c;
    o[c] = f2bf((xs[c] - mu) * rs * g[col] + b[col]);
  }
  *(ushort4*)(out + (size_t)row * EMBED + tid * 4) = *(const ushort4*)o;
}

// ======== 256x256 8-wave 4-phase GEMM v3 (m201-skeleton phases) ========
template <int EPI>
__global__ __launch_bounds__(512, 2) void k_gemm8(
    const unsigned short* __restrict__ A, const unsigned short* __restrict__ Bt,
    const float* __restrict__ bias, const float* __restrict__ resid,
    float* __restrict__ outf, unsigned short* __restrict__ outb,
    int M, int N, int K) {
  __shared__ unsigned short lA[2][16384];
  __shared__ unsigned short lB[2][16384];
  int tid = threadIdx.x;
  int nwg = gridDim.x * gridDim.y;
  int bid = blockIdx.y * gridDim.x + blockIdx.x;
  int swz = (bid & 7) * (nwg >> 3) + (bid >> 3);
  int m0 = (swz / gridDim.x) * 256, n0 = (swz % gridDim.x) * 256;
  int lane = tid & 63, w = tid >> 6;
  int lr = lane & 15, lg = lane >> 4;
  int warow = (w >> 2) * 64;  // A row base within a half
  int wbrow = (w & 3) * 32;   // B row base within a half
  int rx = lr & 7;
  int colk[2] = {(lg ^ rx) * 8, ((4 + lg) ^ rx) * 8};
  f32x4 acc[8][4] = {};
  int swzk = ((lane & 7) ^ ((lane >> 3) & 7)) * 8;  // pre-swizzled global col (shorts)
  const unsigned short* gA[2];
  const unsigned short* gB[2];
#pragma unroll
  for (int i = 0; i < 2; i++) {
    int chrow = (w * 2 + i) * 8 + (lane >> 3);
    gA[i] = A + (size_t)(m0 + chrow) * K + swzk;
    gB[i] = Bt + (size_t)(n0 + chrow) * K + swzk;
  }
  int NT = K >> 6;
  auto stageA = [&](int h, int kt, int buf) {
    size_t goff = (size_t)(h * 128) * K + (size_t)kt * 64;
    int lo = h * 8192 + w * 1024;
    gload_lds16(gA[0] + goff, &lA[buf][lo]);
    gload_lds16(gA[1] + goff, &lA[buf][lo + 512]);
  };
  auto stageB = [&](int h, int kt, int buf) {
    size_t goff = (size_t)(h * 128) * K + (size_t)kt * 64;
    int lo = h * 8192 + w * 1024;
    gload_lds16(gB[0] + goff, &lB[buf][lo]);
    gload_lds16(gB[1] + goff, &lB[buf][lo + 512]);
  };
  bf16x8 aX[4][2], aY[4][2], b0[2][2], b1[2][2];
  auto rdA = [&](int buf, int mh, bf16x8 (&dst)[4][2]) {
#pragma unroll
    for (int ii = 0; ii < 4; ii++) {
      int ra = mh * 128 + warow + ii * 16 + lr;
#pragma unroll
      for (int ks = 0; ks < 2; ks++)
        dst[ii][ks] = *(const bf16x8*)&lA[buf][ra * 64 + colk[ks]];
    }
  };
  auto rdB = [&](int buf, int nh, bf16x8 (&dst)[2][2]) {
#pragma unroll
    for (int jj = 0; jj < 2; jj++) {
      int rb = nh * 128 + wbrow + jj * 16 + lr;
#pragma unroll
      for (int ks = 0; ks < 2; ks++)
        dst[jj][ks] = *(const bf16x8*)&lB[buf][rb * 64 + colk[ks]];
    }
  };
  auto mf = [&](int mh, int nh, bf16x8 (&aa)[4][2], bf16x8 (&bb)[2][2]) {
    __builtin_amdgcn_s_setprio(1);
#pragma unroll
    for (int ii = 0; ii < 4; ii++)
#pragma unroll
      for (int jj = 0; jj < 2; jj++)
#pragma unroll
        for (int ks = 0; ks < 2; ks++)
          acc[mh * 4 + ii][nh * 2 + jj] =
              MFMA16(aa[ii][ks], bb[jj][ks], acc[mh * 4 + ii][nh * 2 + jj]);
    __builtin_amdgcn_s_setprio(0);
  };
  stageA(0, 0, 0); stageB(0, 0, 0);   // G1(0)
  stageB(1, 0, 0); stageA(1, 0, 0);   // G2(0)
  wait_vmcnt<4>();
  __builtin_amdgcn_s_barrier();
  rdA(0, 0, aX);
  for (int t = 0; t < NT - 1; t++) {
    int cur = t & 1, nxt = cur ^ 1;
    rdB(cur, 0, b0);
    stageA(0, t + 1, nxt); stageB(0, t + 1, nxt);
    wait_vmcnt<4>();
    __builtin_amdgcn_s_barrier();
    lds_fence();
    mf(0, 0, aX, b0);
    rdB(cur, 1, b1);
    rdA(cur, 1, aY);
    __builtin_amdgcn_s_barrier();
    lds_fence();
    mf(0, 1, aX, b1);
    stageB(1, t + 1, nxt); stageA(1, t + 1, nxt);
    wait_vmcnt<4>();
    __builtin_amdgcn_s_barrier();
    lds_fence();
    mf(1, 1, aY, b1);
    rdA(nxt, 0, aX);
    __builtin_amdgcn_s_barrier();
    lds_fence();
    mf(1, 0, aY, b0);
  }
  {  // tail tile NT-1: no staging; drain remaining G2(NT-2) then finish
    int cur = (NT - 1) & 1;
    rdB(cur, 0, b0);
    wait_vmcnt<0>();
    __builtin_amdgcn_s_barrier();
    lds_fence();
    mf(0, 0, aX, b0);
    rdB(cur, 1, b1);
    rdA(cur, 1, aY);
    lds_fence();
    mf(0, 1, aX, b1);
    mf(1, 1, aY, b1);
    mf(1, 0, aY, b0);
  }
#pragma unroll
  for (int i = 0; i < 8; i++) {
#pragma unroll
    for (int j = 0; j < 4; j++) {
      int col = n0 + (j >> 1) * 128 + wbrow + (j & 1) * 16 + lr;
      float bv = bias[col];
#pragma unroll
      for (int r = 0; r < 4; r++) {
        int row = m0 + (i >> 2) * 128 + warow + (i & 3) * 16 + lg * 4 + r;
        float v = acc[i][j][r] + bv;
        size_t idx = (size_t)row * N + col;
        if constexpr (EPI == 0) {
          outb[idx] = f2bf(v);
        } else if constexpr (EPI == 1) {
          outf[idx] = v + resid[idx];
        } else {
          float gv = 0.5f * v * (1.0f + erff(v * 0.70710678118654752f));
          outb[idx] = f2bf(gv);
        }
      }
    }
  }
}

// ---- narrow GEMM (BM=128, BN=64, BK=64): 3-buffer counted-vmcnt pipeline ----
template <int EPI>
__global__ __launch_bounds__(256) void k_gemmN(
    const unsigned short* __restrict__ A, const unsigned short* __restrict__ Bt,
    const float* __restrict__ bias, const float* __restrict__ resid,
    float* __restrict__ outf, unsigned short* __restrict__ outb,
    int M, int N, int K) {
  __shared__ unsigned short lA[3][128 * 64];
  __shared__ unsigned short lB[3][64 * 64];
  int tid = threadIdx.x;
  int nwg = gridDim.x * gridDim.y;
  int bid = blockIdx.y * gridDim.x + blockIdx.x;
  int swz = (bid & 7) * (nwg >> 3) + (bid >> 3);
  int m0 = (swz / gridDim.x) * 128, n0 = (swz % gridDim.x) * 64;
  int lane = tid & 63, w = tid >> 6;
  int wm = w * 32;
  int lr = lane & 15, lg = lane >> 4;
  int rx = lr & 7;
  int colk[2] = {(lg ^ rx) * 8, ((4 + lg) ^ rx) * 8};
  f32x4 acc[2][4] = {};
  int swzk = ((lane & 7) ^ ((lane >> 3) & 7)) * 8;  // pre-swizzled global col (shorts)
  const unsigned short* gsrc[6];
  int loff[6];
  bool isa[6];
#pragma unroll
  for (int c0 = 0; c0 < 6; c0++) {
    int c = w * 6 + c0;
    if (c < 16) {
      int row = c * 8 + (lane >> 3);
      gsrc[c0] = A + (size_t)(m0 + row) * K + swzk;
      loff[c0] = c * 512;
      isa[c0] = true;
    } else {
      int row = (c - 16) * 8 + (lane >> 3);
      gsrc[c0] = Bt + (size_t)(n0 + row) * K + swzk;
      loff[c0] = (c - 16) * 512;
      isa[c0] = false;
    }
  }
  auto stage = [&](int k0, int buf) {
#pragma unroll
    for (int c0 = 0; c0 < 6; c0++)
      gload_lds16(gsrc[c0] + k0, isa[c0] ? &lA[buf][loff[c0]] : &lB[buf][loff[c0]]);
  };
  auto compute = [&](int buf) {
    bf16x8 af[2][2], bf[4][2];
#pragma unroll
    for (int i = 0; i < 2; i++)
#pragma unroll
      for (int ks = 0; ks < 2; ks++)
        af[i][ks] = *(const bf16x8*)&lA[buf][(wm + i * 16 + lr) * 64 + colk[ks]];
#pragma unroll
    for (int j = 0; j < 4; j++)
#pragma unroll
      for (int ks = 0; ks < 2; ks++)
        bf[j][ks] = *(const bf16x8*)&lB[buf][(j * 16 + lr) * 64 + colk[ks]];
    __builtin_amdgcn_s_setprio(1);
#pragma unroll
    for (int i = 0; i < 2; i++)
#pragma unroll
      for (int j = 0; j < 4; j++)
#pragma unroll
        for (int ks = 0; ks < 2; ks++)
          acc[i][j] = MFMA16(af[i][ks], bf[j][ks], acc[i][j]);
    __builtin_amdgcn_s_setprio(0);
  };
  int nt = K >> 6;
  stage(0, 0);
  stage(64, 1);
  wait_vmcnt<6>();
  __builtin_amdgcn_s_barrier();
  int c0 = 0, c1 = 1, c2 = 2;
  for (int t = 0; t < nt - 2; t++) {
    stage((t + 2) * 64, c2);
    compute(c0);
    wait_vmcnt<6>();
    __builtin_amdgcn_s_barrier();
    int tmp = c0; c0 = c1; c1 = c2; c2 = tmp;
  }
  compute(c0);
  wait_vmcnt<0>();
  __builtin_amdgcn_s_barrier();
  compute(c1);
#pragma unroll
  for (int i = 0; i < 2; i++) {
#pragma unroll
    for (int j = 0; j < 4; j++) {
      int colb = n0 + j * 16 + lr;
      float bv = bias[colb];
#pragma unroll
      for (int r = 0; r < 4; r++) {
        int row = m0 + wm + i * 16 + lg * 4 + r;
        float v = acc[i][j][r] + bv;
        size_t idx = (size_t)row * N + colb;
        if constexpr (EPI == 0) {
          outb[idx] = f2bf(v);
        } else if constexpr (EPI == 1) {
          outf[idx] = v + resid[idx];
        } else {
          float gv = 0.5f * v * (1.0f + erff(v * 0.70710678118654752f));
          outb[idx] = f2bf(gv);
        }
      }
    }
  }
}

// ---------------- causal flash attention, KV-split (QBLK=32, 4 waves) ----------------
// Wave (qh = w>>1, p = w&1): q-rows [qt'*32 + qh*16, +16), kv tiles p, p+2, ...
// Chain halves vs R17 (max 16 iters). Block-cooperative pair staging (8 gloads/wave),
// vm0-dbuf skeleton. Final fp32-exact merge of parity partials via LDS (stride 25).
// nkv = (qt'>>1)+1; no wave-level fully-masked tiles exist by construction.
__global__ __launch_bounds__(256) void k_attention(
    const unsigned short* __restrict__ qkv, const unsigned short* __restrict__ Vt,
    unsigned short* __restrict__ out) {
  __shared__ unsigned short lK[2][2][4096];  // [buf][tile parity][64x64 pre-swizzled]
  __shared__ unsigned short lV[2][2][4096];
  __shared__ unsigned short lP[4][16][72];
  int bid = blockIdx.x;
  int i = bid >> 3;
  int qt = 63 - (i >> 2);                // 32-row q-tile, big first
  int bh = (bid & 7) * 4 + (i & 3);
  int b = bh >> 4, h = bh & 15;
  int tid = threadIdx.x, lane = tid & 63, w = tid >> 6;
  int qh = w >> 1, p = w & 1;
  int lr = lane & 15, lg = lane >> 4;
  const unsigned short* base = qkv + (size_t)b * SEQ * THREE_EMBED + h * HDIM;
  const unsigned short* Kb = base + EMBED;
  const unsigned short* Vb = Vt + (size_t)bh * HDIM * SEQ;
  int q0 = qt * 32 + qh * 16;
  const float SCL = 0.125f * 1.4426950408889634f;  // 1/sqrt(64) * log2(e)
  bf16x8 qf[2];
  {
    int qrow = q0 + lr;
    bf16x8 r0 = *(const bf16x8*)(base + (size_t)qrow * THREE_EMBED + lg * 8);
    bf16x8 r1 = *(const bf16x8*)(base + (size_t)qrow * THREE_EMBED + 32 + lg * 8);
#pragma unroll
    for (int j = 0; j < 8; j++) {
      qf[0][j] = (short)f2bf(bf2f((unsigned short)r0[j]) * SCL);
      qf[1][j] = (short)f2bf(bf2f((unsigned short)r1[j]) * SCL);
    }
  }
  bf16x8 ones;
  {
    short o1 = 0x3F80;
#pragma unroll
    for (int j = 0; j < 8; j++) ones[j] = o1;
  }
  f32x4 o[4] = {};
  f32x4 osum = {};
  float m_[4] = {-INFINITY, -INFINITY, -INFINITY, -INFINITY};
  int srow = lane >> 3;
  int scol = ((lane & 7) ^ (lane >> 3)) * 8;  // pre-swizzled source col (shorts)
  int nkv = (qt >> 1) + 1;
  int npairs = (nkv + 1) >> 1;
  // pair staging: 32 chunks (2 tiles x {K,V} x 8 sub-chunks); wave w owns [w*8, w*8+8)
  auto stagePair = [&](int j, int buf) {
#pragma unroll
    for (int c0 = 0; c0 < 8; c0++) {
      int c = w * 8 + c0;
      int ts = c >> 4;           // tile parity slot
      int kt = 2 * j + ts;
      if (kt >= nkv) continue;
      int isV = (c >> 3) & 1;
      int sub = c & 7;
      int row = sub * 8 + srow;
      if (!isV)
        gload_lds16(Kb + (size_t)(kt * 64 + row) * THREE_EMBED + scol, &lK[buf][ts][sub * 512]);
      else
        gload_lds16(Vb + (size_t)row * SEQ + kt * 64 + scol, &lV[buf][ts][sub * 512]);
    }
  };
  stagePair(0, 0);
  wait_vm0_barrier();
  int buf = 0;
  for (int j = 0; j < npairs; j++) {
    if (j + 1 < npairs) stagePair(j + 1, buf ^ 1);
    int kt = 2 * j + p;
    if (kt < nkv) {
      __builtin_amdgcn_s_setprio(1);
      f32x4 s[4];
#pragma unroll
      for (int ct = 0; ct < 4; ct++) {
        int krow = ct * 16 + lr;
        int sw = (krow & 7) << 3;
        bf16x8 k0 = *(const bf16x8*)&lK[buf][p][krow * 64 + ((lg * 8) ^ sw)];
        bf16x8 k1 = *(const bf16x8*)&lK[buf][p][krow * 64 + ((32 + lg * 8) ^ sw)];
        f32x4 z = {};
        z = MFMA16(qf[0], k0, z);
        s[ct] = MFMA16(qf[1], k1, z);
      }
      __builtin_amdgcn_s_setprio(0);
      bool maskt = (kt * 64 + 63 > q0);
      float pm[4] = {-INFINITY, -INFINITY, -INFINITY, -INFINITY};
#pragma unroll
      for (int ct = 0; ct < 4; ct++) {
#pragma unroll
        for (int r = 0; r < 4; r++) {
          float sv = s[ct][r];  // SCL pre-folded into Q
          if (maskt) {
            int kg = kt * 64 + ct * 16 + lr;
            int qg = q0 + lg * 4 + r;
            if (kg > qg) sv = -INFINITY;
          }
          s[ct][r] = sv;
          pm[r] = fmaxf(pm[r], sv);
        }
      }
      float dm = fmaxf(fmaxf(pm[0] - m_[0], pm[1] - m_[1]),
                       fmaxf(pm[2] - m_[2], pm[3] - m_[3]));
      if (!__all(dm <= 8.0f)) {
#pragma unroll
        for (int r = 0; r < 4; r++) {
          float mx = pm[r];
          mx = fmaxf(mx, __shfl_xor(mx, 1));
          mx = fmaxf(mx, __shfl_xor(mx, 2));
          mx = fmaxf(mx, __shfl_xor(mx, 4));
          mx = fmaxf(mx, __shfl_xor(mx, 8));
          float mn = fmaxf(m_[r], mx);
          float al = exp2f(m_[r] - mn);
          m_[r] = mn;
          osum[r] *= al;
#pragma unroll
          for (int dt = 0; dt < 4; dt++) o[dt][r] *= al;
        }
      }
      // P = exp2(S - m) -> bf16 via cvt_pk pairs -> LDS
#pragma unroll
      for (int ct = 0; ct < 4; ct++) {
#pragma unroll
        for (int rp = 0; rp < 2; rp++) {
          float p0 = exp2f(s[ct][2 * rp] - m_[2 * rp]);
          float p1 = exp2f(s[ct][2 * rp + 1] - m_[2 * rp + 1]);
          unsigned int pk;
          asm("v_cvt_pk_bf16_f32 %0, %1, %2" : "=v"(pk) : "v"(p0), "v"(p1));
          lP[w][lg * 4 + 2 * rp][ct * 16 + lr] = (unsigned short)pk;
          lP[w][lg * 4 + 2 * rp + 1][ct * 16 + lr] = (unsigned short)(pk >> 16);
        }
      }
      __builtin_amdgcn_s_setprio(1);
#pragma unroll
      for (int ks = 0; ks < 2; ks++) {
        bf16x8 pf = *(const bf16x8*)&lP[w][lr][ks * 32 + lg * 8];
        osum = MFMA16(pf, ones, osum);
#pragma unroll
        for (int dt = 0; dt < 4; dt++) {
          int vrow = dt * 16 + lr;
          int sw = (vrow & 7) << 3;
          bf16x8 vf = *(const bf16x8*)&lV[buf][p][vrow * 64 + ((ks * 32 + lg * 8) ^ sw)];
          o[dt] = MFMA16(pf, vf, o[dt]);
        }
      }
      __builtin_amdgcn_s_setprio(0);
    }
    wait_vm0_barrier();
    buf ^= 1;
  }
  // ---- merge parity partials (exact in fp32) ----
  float* pb = (float*)&lK[0][0][0] + qh * 1600;  // 64 lanes x 25 floats per qh
  if (p == 1) {
    float* dst = pb + lane * 25;
#pragma unroll
    for (int dt = 0; dt < 4; dt++)
#pragma unroll
      for (int r = 0; r < 4; r++) dst[dt * 4 + r] = o[dt][r];
#pragma unroll
    for (int r = 0; r < 4; r++) { dst[16 + r] = osum[r]; dst[20 + r] = m_[r]; }
  }
  __syncthreads();
  if (p == 0) {
    const float* src = pb + lane * 25;
#pragma unroll
    for (int r = 0; r < 4; r++) {
      float m1 = src[20 + r];
      float M = fmaxf(m_[r], m1);
      float s0 = exp2f(m_[r] - M);
      float s1 = exp2f(m1 - M);
      osum[r] = osum[r] * s0 + src[16 + r] * s1;
#pragma unroll
      for (int dt = 0; dt < 4; dt++)
        o[dt][r] = o[dt][r] * s0 + src[dt * 4 + r] * s1;
    }
#pragma unroll
    for (int dt = 0; dt < 4; dt++)
#pragma unroll
      for (int r = 0; r < 4; r++) {
        int row = q0 + lg * 4 + r;
        float val = o[dt][r] / osum[r];
        out[(size_t)(b * SEQ + row) * EMBED + h * HDIM + dt * 16 + lr] = f2bf(val);
      }
  }
}

extern "C" void kernel_launch(void* const* d_in, const int* in_sizes, int n_in,
                              void* d_out, int out_size, void* d_ws, size_t ws_size,
                              hipStream_t stream) {
  const float* x      = (const float*)d_in[0];
  const float* ln1_g  = (const float*)d_in[1];
  const float* ln1_b  = (const float*)d_in[2];
  const float* w_attn = (const float*)d_in[3];
  const float* b_attn = (const float*)d_in[4];
  const float* w_proj = (const float*)d_in[5];
  const float* b_proj = (const float*)d_in[6];
  const float* ln2_g  = (const float*)d_in[7];
  const float* ln2_b  = (const float*)d_in[8];
  const float* w_fc   = (const float*)d_in[9];
  const float* b_fc   = (const float*)d_in[10];
  const float* w_fc2  = (const float*)d_in[11];
  const float* b_fc2  = (const float*)d_in[12];
  float* outp = (float*)d_out;

  char* ws = (char*)d_ws;
  unsigned short* wT_attn = (unsigned short*)(ws);             // [3072][1024] bf16, 6 MB
  unsigned short* wT_proj = (unsigned short*)(ws + 6291456);   // [1024][1024] bf16, 2 MB
  unsigned short* wT_fc   = (unsigned short*)(ws + 8388608);   // [4096][1024] bf16, 8 MB
  unsigned short* wT_fc2  = (unsigned short*)(ws + 16777216);  // [1024][4096] bf16, 8 MB
  unsigned short* buf1    = (unsigned short*)(ws + 25165824);  // 8 MB: xln -> attnout -> x2ln
  float*          x1      = (float*)(ws + 33554432);           // 16 MB fp32 (written after attention)
  unsigned short* Vt      = (unsigned short*)(ws + 33554432);  // 8 MB bf16, dead once attention done
  unsigned short* qkv_h   = (unsigned short*)(ws + 50331648);  // 24 MB qkv -> 32 MB h (48..80 MB)

  dim3 blk(256);
  // all 4 weight transposes in one launch (12288 blocks)
  k_transpose_all<<<dim3(12288), blk, 0, stream>>>(
      w_attn, w_proj, w_fc, w_fc2, wT_attn, wT_proj, wT_fc, wT_fc2);
  // LN1: x -> xln (buf1)
  k_layernorm<<<dim3(MTOT), blk, 0, stream>>>(x, ln1_g, ln1_b, buf1);
  // QKV: 256^2 v3, 12x16 = 192 blocks
  k_gemm8<0><<<dim3(THREE_EMBED / 256, MTOT / 256), dim3(512), 0, stream>>>(
      buf1, wT_attn, b_attn, nullptr, nullptr, qkv_h, MTOT, THREE_EMBED, EMBED);
  // V transpose for attention
  k_transpose_v<<<dim3(SEQ / 32, 2 * BATCH * HEADS), blk, 0, stream>>>(qkv_h, Vt);
  // attention -> attnout (buf1): 64 q-tiles x 32 bh = 2048 blocks, KV-split
  k_attention<<<dim3(2048), blk, 0, stream>>>(qkv_h, Vt, buf1);
  // proj + residual: narrow BK=64, 16x32 = 512 blocks (overwrites Vt — dead)
  k_gemmN<1><<<dim3(EMBED / 64, MTOT / 128), blk, 0, stream>>>(
      buf1, wT_proj, b_proj, x, x1, nullptr, MTOT, EMBED, EMBED);
  // LN2: x1 -> x2ln (buf1)
  k_layernorm<<<dim3(MTOT), blk, 0, stream>>>(x1, ln2_g, ln2_b, buf1);
  // FC1 + GELU: 256^2 v3, 16x16 = 256 blocks
  k_gemm8<2><<<dim3(4 * EMBED / 256, MTOT / 256), dim3(512), 0, stream>>>(
      buf1, wT_fc, b_fc, nullptr, nullptr, qkv_h, MTOT, 4 * EMBED, EMBED);
  // FC2 + residual -> out: narrow BK=64, 512 blocks
  k_gemmN<1><<<dim3(EMBED / 64, MTOT / 128), blk, 0, stream>>>(
      qkv_h, wT_fc2, b_fc2, x1, outp, nullptr, MTOT, EMBED, 4 * EMBED);
}

// Round 19
// 250.155 us; speedup vs baseline: 1.0028x; 1.0028x over previous
//
#include <hip/hip_runtime.h>

#define EMBED 1024
#define THREE_EMBED 3072
#define HEADS 16
#define HDIM 64
#define SEQ 2048
#define BATCH 2
#define MTOT 4096  // B*T

typedef short bf16x8 __attribute__((ext_vector_type(8)));
typedef float f32x4 __attribute__((ext_vector_type(4)));

#define MFMA16(a, b, c) __builtin_amdgcn_mfma_f32_16x16x32_bf16(a, b, c, 0, 0, 0)

__device__ __forceinline__ unsigned short f2bf(float f) {
  union { float f; unsigned int u; } v; v.f = f;
  unsigned int r = v.u + 0x7fffu + ((v.u >> 16) & 1u);
  return (unsigned short)(r >> 16);
}

__device__ __forceinline__ float bf2f(unsigned short u) {
  union { unsigned int u; float f; } v;
  v.u = (unsigned int)u << 16;
  return v.f;
}

// async 16B global->LDS. LDS dest is wave-uniform base + lane*16 (HW semantics).
__device__ __forceinline__ void gload_lds16(const unsigned short* g, unsigned short* l) {
  __builtin_amdgcn_global_load_lds(
      (const __attribute__((address_space(1))) void*)g,
      (__attribute__((address_space(3))) void*)l, 16, 0, 0);
}

__device__ __forceinline__ void wait_vm0_barrier() {
  asm volatile("s_waitcnt vmcnt(0)" ::: "memory");
  __builtin_amdgcn_s_barrier();
}

template <int N>
__device__ __forceinline__ void wait_vmcnt() {
  if constexpr (N == 0) asm volatile("s_waitcnt vmcnt(0)" ::: "memory");
  else if constexpr (N == 1) asm volatile("s_waitcnt vmcnt(1)" ::: "memory");
  else if constexpr (N == 2) asm volatile("s_waitcnt vmcnt(2)" ::: "memory");
  else if constexpr (N == 3) asm volatile("s_waitcnt vmcnt(3)" ::: "memory");
  else if constexpr (N == 4) asm volatile("s_waitcnt vmcnt(4)" ::: "memory");
  else if constexpr (N == 6) asm volatile("s_waitcnt vmcnt(6)" ::: "memory");
  else if constexpr (N == 8) asm volatile("s_waitcnt vmcnt(8)" ::: "memory");
}

// after-barrier LDS fence: wait all ds_reads issued pre-barrier, pin MFMA below (rule #18)
__device__ __forceinline__ void lds_fence() {
  asm volatile("s_waitcnt lgkmcnt(0)" ::: "memory");
  __builtin_amdgcn_sched_barrier(0);
}

// ---- merged weight transpose: fp32 [K][N] -> bf16 [N][K], 4 segments, 1 launch ----
__global__ __launch_bounds__(256) void k_transpose_all(
    const float* __restrict__ w_attn, const float* __restrict__ w_proj,
    const float* __restrict__ w_fc, const float* __restrict__ w_fc2,
    unsigned short* __restrict__ o_attn, unsigned short* __restrict__ o_proj,
    unsigned short* __restrict__ o_fc, unsigned short* __restrict__ o_fc2) {
  __shared__ float t[32][33];
  int bid = blockIdx.x;
  const float* in;
  unsigned short* out;
  int K, N, lid;
  if (bid < 3072) {
    in = w_attn; out = o_attn; K = 1024; N = 3072; lid = bid;
  } else if (bid < 4096) {
    in = w_proj; out = o_proj; K = 1024; N = 1024; lid = bid - 3072;
  } else if (bid < 8192) {
    in = w_fc; out = o_fc; K = 1024; N = 4096; lid = bid - 4096;
  } else {
    in = w_fc2; out = o_fc2; K = 4096; N = 1024; lid = bid - 8192;
  }
  int gx = N >> 5;
  int n0 = (lid % gx) * 32, k0 = (lid / gx) * 32;
  int tx = threadIdx.x & 31, ty = threadIdx.x >> 5;
#pragma unroll
  for (int i = 0; i < 32; i += 8)
    t[ty + i][tx] = in[(size_t)(k0 + ty + i) * N + n0 + tx];
  __syncthreads();
#pragma unroll
  for (int i = 0; i < 32; i += 8)
    out[(size_t)(n0 + ty + i) * K + k0 + tx] = f2bf(t[tx][ty + i]);
}

// ---------------- V transpose: qkv V-part -> Vt[bh][64][2048] bf16 ----------------
__global__ __launch_bounds__(256) void k_transpose_v(
    const unsigned short* __restrict__ qkv, unsigned short* __restrict__ Vt) {
  __shared__ unsigned short t[32][33];
  int tx = threadIdx.x & 31, ty = threadIdx.x >> 5;  // 32 x 8
  int t0 = blockIdx.x * 32;
  int d0 = (blockIdx.y & 1) * 32;
  int bh = blockIdx.y >> 1;
  int b = bh >> 4, h = bh & 15;
  const unsigned short* src = qkv + (size_t)b * SEQ * THREE_EMBED + 2 * EMBED + h * HDIM;
#pragma unroll
  for (int i = 0; i < 32; i += 8)
    t[ty + i][tx] = src[(size_t)(t0 + ty + i) * THREE_EMBED + d0 + tx];
  __syncthreads();
  unsigned short* dst = Vt + (size_t)bh * HDIM * SEQ;
#pragma unroll
  for (int i = 0; i < 32; i += 8)
    dst[(size_t)(d0 + ty + i) * SEQ + t0 + tx] = t[tx][ty + i];
}

// ---------------- layernorm fp32 [4096][1024] -> bf16 ----------------
__global__ __launch_bounds__(256) void k_layernorm(
    const float* __restrict__ x, const float* __restrict__ g,
    const float* __restrict__ b, unsigned short* __restrict__ out) {
  int row = blockIdx.x;
  int tid = threadIdx.x;
  const float4 xv = *(const float4*)(x + (size_t)row * EMBED + tid * 4);
  float s = xv.x + xv.y + xv.z + xv.w;
  float sq = xv.x * xv.x + xv.y * xv.y + xv.z * xv.z + xv.w * xv.w;
#pragma unroll
  for (int off = 1; off < 64; off <<= 1) {
    s += __shfl_xor(s, off);
    sq += __shfl_xor(sq, off);
  }
  __shared__ float red[8];
  int w = tid >> 6;
  if ((tid & 63) == 0) { red[w] = s; red[4 + w] = sq; }
  __syncthreads();
  s = red[0] + red[1] + red[2] + red[3];
  sq = red[4] + red[5] + red[6] + red[7];
  float mu = s * (1.0f / EMBED);
  float var = sq * (1.0f / EMBED) - mu * mu;
  float rs = rsqrtf(var + 1e-5f);
  float xs[4] = {xv.x, xv.y, xv.z, xv.w};
  unsigned short o[4];
#pragma unroll
  for (int c = 0; c < 4; c++) {
    int col = tid * 4 + c;
    o[c] = f2bf((xs[c] - mu) * rs * g[col] + b[col]);
  }
  *(ushort4*)(out + (size_t)row * EMBED + tid * 4) = *(const ushort4*)o;
}

// ======== 256x256 8-wave 4-phase GEMM v3 (m201-skeleton phases) ========
template <int EPI>
__global__ __launch_bounds__(512, 2) void k_gemm8(
    const unsigned short* __restrict__ A, const unsigned short* __restrict__ Bt,
    const float* __restrict__ bias, const float* __restrict__ resid,
    float* __restrict__ outf, unsigned short* __restrict__ outb,
    int M, int N, int K) {
  __shared__ unsigned short lA[2][16384];
  __shared__ unsigned short lB[2][16384];
  int tid = threadIdx.x;
  int nwg = gridDim.x * gridDim.y;
  int bid = blockIdx.y * gridDim.x + blockIdx.x;
  int swz = (bid & 7) * (nwg >> 3) + (bid >> 3);
  int m0 = (swz / gridDim.x) * 256, n0 = (swz % gridDim.x) * 256;
  int lane = tid & 63, w = tid >> 6;
  int lr = lane & 15, lg = lane >> 4;
  int warow = (w >> 2) * 64;  // A row base within a half
  int wbrow = (w & 3) * 32;   // B row base within a half
  int rx = lr & 7;
  int colk[2] = {(lg ^ rx) * 8, ((4 + lg) ^ rx) * 8};
  f32x4 acc[8][4] = {};
  int swzk = ((lane & 7) ^ ((lane >> 3) & 7)) * 8;  // pre-swizzled global col (shorts)
  const unsigned short* gA[2];
  const unsigned short* gB[2];
#pragma unroll
  for (int i = 0; i < 2; i++) {
    int chrow = (w * 2 + i) * 8 + (lane >> 3);
    gA[i] = A + (size_t)(m0 + chrow) * K + swzk;
    gB[i] = Bt + (size_t)(n0 + chrow) * K + swzk;
  }
  int NT = K >> 6;
  auto stageA = [&](int h, int kt, int buf) {
    size_t goff = (size_t)(h * 128) * K + (size_t)kt * 64;
    int lo = h * 8192 + w * 1024;
    gload_lds16(gA[0] + goff, &lA[buf][lo]);
    gload_lds16(gA[1] + goff, &lA[buf][lo + 512]);
  };
  auto stageB = [&](int h, int kt, int buf) {
    size_t goff = (size_t)(h * 128) * K + (size_t)kt * 64;
    int lo = h * 8192 + w * 1024;
    gload_lds16(gB[0] + goff, &lB[buf][lo]);
    gload_lds16(gB[1] + goff, &lB[buf][lo + 512]);
  };
  bf16x8 aX[4][2], aY[4][2], b0[2][2], b1[2][2];
  auto rdA = [&](int buf, int mh, bf16x8 (&dst)[4][2]) {
#pragma unroll
    for (int ii = 0; ii < 4; ii++) {
      int ra = mh * 128 + warow + ii * 16 + lr;
#pragma unroll
      for (int ks = 0; ks < 2; ks++)
        dst[ii][ks] = *(const bf16x8*)&lA[buf][ra * 64 + colk[ks]];
    }
  };
  auto rdB = [&](int buf, int nh, bf16x8 (&dst)[2][2]) {
#pragma unroll
    for (int jj = 0; jj < 2; jj++) {
      int rb = nh * 128 + wbrow + jj * 16 + lr;
#pragma unroll
      for (int ks = 0; ks < 2; ks++)
        dst[jj][ks] = *(const bf16x8*)&lB[buf][rb * 64 + colk[ks]];
    }
  };
  auto mf = [&](int mh, int nh, bf16x8 (&aa)[4][2], bf16x8 (&bb)[2][2]) {
    __builtin_amdgcn_s_setprio(1);
#pragma unroll
    for (int ii = 0; ii < 4; ii++)
#pragma unroll
      for (int jj = 0; jj < 2; jj++)
#pragma unroll
        for (int ks = 0; ks < 2; ks++)
          acc[mh * 4 + ii][nh * 2 + jj] =
              MFMA16(aa[ii][ks], bb[jj][ks], acc[mh * 4 + ii][nh * 2 + jj]);
    __builtin_amdgcn_s_setprio(0);
  };
  stageA(0, 0, 0); stageB(0, 0, 0);   // G1(0)
  stageB(1, 0, 0); stageA(1, 0, 0);   // G2(0)
  wait_vmcnt<4>();
  __builtin_amdgcn_s_barrier();
  rdA(0, 0, aX);
  for (int t = 0; t < NT - 1; t++) {
    int cur = t & 1, nxt = cur ^ 1;
    rdB(cur, 0, b0);
    stageA(0, t + 1, nxt); stageB(0, t + 1, nxt);
    wait_vmcnt<4>();
    __builtin_amdgcn_s_barrier();
    lds_fence();
    mf(0, 0, aX, b0);
    rdB(cur, 1, b1);
    rdA(cur, 1, aY);
    __builtin_amdgcn_s_barrier();
    lds_fence();
    mf(0, 1, aX, b1);
    stageB(1, t + 1, nxt); stageA(1, t + 1, nxt);
    wait_vmcnt<4>();
    __builtin_amdgcn_s_barrier();
    lds_fence();
    mf(1, 1, aY, b1);
    rdA(nxt, 0, aX);
    __builtin_amdgcn_s_barrier();
    lds_fence();
    mf(1, 0, aY, b0);
  }
  {  // tail tile NT-1: no staging; drain remaining G2(NT-2) then finish
    int cur = (NT - 1) & 1;
    rdB(cur, 0, b0);
    wait_vmcnt<0>();
    __builtin_amdgcn_s_barrier();
    lds_fence();
    mf(0, 0, aX, b0);
    rdB(cur, 1, b1);
    rdA(cur, 1, aY);
    lds_fence();
    mf(0, 1, aX, b1);
    mf(1, 1, aY, b1);
    mf(1, 0, aY, b0);
  }
#pragma unroll
  for (int i = 0; i < 8; i++) {
#pragma unroll
    for (int j = 0; j < 4; j++) {
      int col = n0 + (j >> 1) * 128 + wbrow + (j & 1) * 16 + lr;
      float bv = bias[col];
#pragma unroll
      for (int r = 0; r < 4; r++) {
        int row = m0 + (i >> 2) * 128 + warow + (i & 3) * 16 + lg * 4 + r;
        float v = acc[i][j][r] + bv;
        size_t idx = (size_t)row * N + col;
        if constexpr (EPI == 0) {
          outb[idx] = f2bf(v);
        } else if constexpr (EPI == 1) {
          outf[idx] = v + resid[idx];
        } else {
          float gv = 0.5f * v * (1.0f + erff(v * 0.70710678118654752f));
          outb[idx] = f2bf(gv);
        }
      }
    }
  }
}

// ---- narrow GEMM (BM=128, BN=64, BK=64): 3-buffer counted-vmcnt pipeline ----
template <int EPI>
__global__ __launch_bounds__(256) void k_gemmN(
    const unsigned short* __restrict__ A, const unsigned short* __restrict__ Bt,
    const float* __restrict__ bias, const float* __restrict__ resid,
    float* __restrict__ outf, unsigned short* __restrict__ outb,
    int M, int N, int K) {
  __shared__ unsigned short lA[3][128 * 64];
  __shared__ unsigned short lB[3][64 * 64];
  int tid = threadIdx.x;
  int nwg = gridDim.x * gridDim.y;
  int bid = blockIdx.y * gridDim.x + blockIdx.x;
  int swz = (bid & 7) * (nwg >> 3) + (bid >> 3);
  int m0 = (swz / gridDim.x) * 128, n0 = (swz % gridDim.x) * 64;
  int lane = tid & 63, w = tid >> 6;
  int wm = w * 32;
  int lr = lane & 15, lg = lane >> 4;
  int rx = lr & 7;
  int colk[2] = {(lg ^ rx) * 8, ((4 + lg) ^ rx) * 8};
  f32x4 acc[2][4] = {};
  int swzk = ((lane & 7) ^ ((lane >> 3) & 7)) * 8;  // pre-swizzled global col (shorts)
  const unsigned short* gsrc[6];
  int loff[6];
  bool isa[6];
#pragma unroll
  for (int c0 = 0; c0 < 6; c0++) {
    int c = w * 6 + c0;
    if (c < 16) {
      int row = c * 8 + (lane >> 3);
      gsrc[c0] = A + (size_t)(m0 + row) * K + swzk;
      loff[c0] = c * 512;
      isa[c0] = true;
    } else {
      int row = (c - 16) * 8 + (lane >> 3);
      gsrc[c0] = Bt + (size_t)(n0 + row) * K + swzk;
      loff[c0] = (c - 16) * 512;
      isa[c0] = false;
    }
  }
  auto stage = [&](int k0, int buf) {
#pragma unroll
    for (int c0 = 0; c0 < 6; c0++)
      gload_lds16(gsrc[c0] + k0, isa[c0] ? &lA[buf][loff[c0]] : &lB[buf][loff[c0]]);
  };
  auto compute = [&](int buf) {
    bf16x8 af[2][2], bf[4][2];
#pragma unroll
    for (int i = 0; i < 2; i++)
#pragma unroll
      for (int ks = 0; ks < 2; ks++)
        af[i][ks] = *(const bf16x8*)&lA[buf][(wm + i * 16 + lr) * 64 + colk[ks]];
#pragma unroll
    for (int j = 0; j < 4; j++)
#pragma unroll
      for (int ks = 0; ks < 2; ks++)
        bf[j][ks] = *(const bf16x8*)&lB[buf][(j * 16 + lr) * 64 + colk[ks]];
    __builtin_amdgcn_s_setprio(1);
#pragma unroll
    for (int i = 0; i < 2; i++)
#pragma unroll
      for (int j = 0; j < 4; j++)
#pragma unroll
        for (int ks = 0; ks < 2; ks++)
          acc[i][j] = MFMA16(af[i][ks], bf[j][ks], acc[i][j]);
    __builtin_amdgcn_s_setprio(0);
  };
  int nt = K >> 6;
  stage(0, 0);
  stage(64, 1);
  wait_vmcnt<6>();
  __builtin_amdgcn_s_barrier();
  int c0 = 0, c1 = 1, c2 = 2;
  for (int t = 0; t < nt - 2; t++) {
    stage((t + 2) * 64, c2);
    compute(c0);
    wait_vmcnt<6>();
    __builtin_amdgcn_s_barrier();
    int tmp = c0; c0 = c1; c1 = c2; c2 = tmp;
  }
  compute(c0);
  wait_vmcnt<0>();
  __builtin_amdgcn_s_barrier();
  compute(c1);
#pragma unroll
  for (int i = 0; i < 2; i++) {
#pragma unroll
    for (int j = 0; j < 4; j++) {
      int colb = n0 + j * 16 + lr;
      float bv = bias[colb];
#pragma unroll
      for (int r = 0; r < 4; r++) {
        int row = m0 + wm + i * 16 + lg * 4 + r;
        float v = acc[i][j][r] + bv;
        size_t idx = (size_t)row * N + colb;
        if constexpr (EPI == 0) {
          outb[idx] = f2bf(v);
        } else if constexpr (EPI == 1) {
          outf[idx] = v + resid[idx];
        } else {
          float gv = 0.5f * v * (1.0f + erff(v * 0.70710678118654752f));
          outb[idx] = f2bf(gv);
        }
      }
    }
  }
}

// ---------------- causal flash attention, KV-split (QBLK=32, 4 waves) ----------------
// Wave (qh = w>>1, p = w&1): q-rows [qt'*32 + qh*16, +16), kv tiles p, p+2, ...
// Chain halves vs R17 (max 16 iters). Block-cooperative pair staging (8 gloads/wave),
// vm0-dbuf skeleton. Final fp32-exact merge of parity partials via LDS (stride 25).
// nkv = (qt'>>1)+1; no wave-level fully-masked tiles exist by construction.
__global__ __launch_bounds__(256) void k_attention(
    const unsigned short* __restrict__ qkv, const unsigned short* __restrict__ Vt,
    unsigned short* __restrict__ out) {
  __shared__ unsigned short lK[2][2][4096];  // [buf][tile parity][64x64 pre-swizzled]
  __shared__ unsigned short lV[2][2][4096];
  __shared__ unsigned short lP[4][16][72];
  int bid = blockIdx.x;
  int i = bid >> 3;
  int qt = 63 - (i >> 2);                // 32-row q-tile, big first
  int bh = (bid & 7) * 4 + (i & 3);
  int b = bh >> 4, h = bh & 15;
  int tid = threadIdx.x, lane = tid & 63, w = tid >> 6;
  int qh = w >> 1, p = w & 1;
  int lr = lane & 15, lg = lane >> 4;
  const unsigned short* base = qkv + (size_t)b * SEQ * THREE_EMBED + h * HDIM;
  const unsigned short* Kb = base + EMBED;
  const unsigned short* Vb = Vt + (size_t)bh * HDIM * SEQ;
  int q0 = qt * 32 + qh * 16;
  const float SCL = 0.125f * 1.4426950408889634f;  // 1/sqrt(64) * log2(e)
  bf16x8 qf[2];
  {
    int qrow = q0 + lr;
    bf16x8 r0 = *(const bf16x8*)(base + (size_t)qrow * THREE_EMBED + lg * 8);
    bf16x8 r1 = *(const bf16x8*)(base + (size_t)qrow * THREE_EMBED + 32 + lg * 8);
#pragma unroll
    for (int j = 0; j < 8; j++) {
      qf[0][j] = (short)f2bf(bf2f((unsigned short)r0[j]) * SCL);
      qf[1][j] = (short)f2bf(bf2f((unsigned short)r1[j]) * SCL);
    }
  }
  bf16x8 ones;
  {
    short o1 = 0x3F80;
#pragma unroll
    for (int j = 0; j < 8; j++) ones[j] = o1;
  }
  f32x4 o[4] = {};
  f32x4 osum = {};
  float m_[4] = {-INFINITY, -INFINITY, -INFINITY, -INFINITY};
  int srow = lane >> 3;
  int scol = ((lane & 7) ^ (lane >> 3)) * 8;  // pre-swizzled source col (shorts)
  int nkv = (qt >> 1) + 1;
  int npairs = (nkv + 1) >> 1;
  // pair staging: 32 chunks (2 tiles x {K,V} x 8 sub-chunks); wave w owns [w*8, w*8+8)
  auto stagePair = [&](int j, int buf) {
#pragma unroll
    for (int c0 = 0; c0 < 8; c0++) {
      int c = w * 8 + c0;
      int ts = c >> 4;           // tile parity slot
      int kt = 2 * j + ts;
      if (kt >= nkv) continue;
      int isV = (c >> 3) & 1;
      int sub = c & 7;
      int row = sub * 8 + srow;
      if (!isV)
        gload_lds16(Kb + (size_t)(kt * 64 + row) * THREE_EMBED + scol, &lK[buf][ts][sub * 512]);
      else
        gload_lds16(Vb + (size_t)row * SEQ + kt * 64 + scol, &lV[buf][ts][sub * 512]);
    }
  };
  stagePair(0, 0);
  wait_vm0_barrier();
  int buf = 0;
  for (int j = 0; j < npairs; j++) {
    if (j + 1 < npairs) stagePair(j + 1, buf ^ 1);
    int kt = 2 * j + p;
    if (kt < nkv) {
      __builtin_amdgcn_s_setprio(1);
      f32x4 s[4];
#pragma unroll
      for (int ct = 0; ct < 4; ct++) {
        int krow = ct * 16 + lr;
        int sw = (krow & 7) << 3;
        bf16x8 k0 = *(const bf16x8*)&lK[buf][p][krow * 64 + ((lg * 8) ^ sw)];
        bf16x8 k1 = *(const bf16x8*)&lK[buf][p][krow * 64 + ((32 + lg * 8) ^ sw)];
        f32x4 z = {};
        z = MFMA16(qf[0], k0, z);
        s[ct] = MFMA16(qf[1], k1, z);
      }
      __builtin_amdgcn_s_setprio(0);
      bool maskt = (kt * 64 + 63 > q0);
      float pm[4] = {-INFINITY, -INFINITY, -INFINITY, -INFINITY};
#pragma unroll
      for (int ct = 0; ct < 4; ct++) {
#pragma unroll
        for (int r = 0; r < 4; r++) {
          float sv = s[ct][r];  // SCL pre-folded into Q
          if (maskt) {
            int kg = kt * 64 + ct * 16 + lr;
            int qg = q0 + lg * 4 + r;
            if (kg > qg) sv = -INFINITY;
          }
          s[ct][r] = sv;
          pm[r] = fmaxf(pm[r], sv);
        }
      }
      float dm = fmaxf(fmaxf(pm[0] - m_[0], pm[1] - m_[1]),
                       fmaxf(pm[2] - m_[2], pm[3] - m_[3]));
      if (!__all(dm <= 8.0f)) {
#pragma unroll
        for (int r = 0; r < 4; r++) {
          float mx = pm[r];
          mx = fmaxf(mx, __shfl_xor(mx, 1));
          mx = fmaxf(mx, __shfl_xor(mx, 2));
          mx = fmaxf(mx, __shfl_xor(mx, 4));
          mx = fmaxf(mx, __shfl_xor(mx, 8));
          float mn = fmaxf(m_[r], mx);
          float al = exp2f(m_[r] - mn);
          m_[r] = mn;
          osum[r] *= al;
#pragma unroll
          for (int dt = 0; dt < 4; dt++) o[dt][r] *= al;
        }
      }
      // P = exp2(S - m) -> bf16 via cvt_pk pairs -> LDS
#pragma unroll
      for (int ct = 0; ct < 4; ct++) {
#pragma unroll
        for (int rp = 0; rp < 2; rp++) {
          float p0 = exp2f(s[ct][2 * rp] - m_[2 * rp]);
          float p1 = exp2f(s[ct][2 * rp + 1] - m_[2 * rp + 1]);
          unsigned int pk;
          asm("v_cvt_pk_bf16_f32 %0, %1, %2" : "=v"(pk) : "v"(p0), "v"(p1));
          lP[w][lg * 4 + 2 * rp][ct * 16 + lr] = (unsigned short)pk;
          lP[w][lg * 4 + 2 * rp + 1][ct * 16 + lr] = (unsigned short)(pk >> 16);
        }
      }
      __builtin_amdgcn_s_setprio(1);
#pragma unroll
      for (int ks = 0; ks < 2; ks++) {
        bf16x8 pf = *(const bf16x8*)&lP[w][lr][ks * 32 + lg * 8];
        osum = MFMA16(pf, ones, osum);
#pragma unroll
        for (int dt = 0; dt < 4; dt++) {
          int vrow = dt * 16 + lr;
          int sw = (vrow & 7) << 3;
          bf16x8 vf = *(const bf16x8*)&lV[buf][p][vrow * 64 + ((ks * 32 + lg * 8) ^ sw)];
          o[dt] = MFMA16(pf, vf, o[dt]);
        }
      }
      __builtin_amdgcn_s_setprio(0);
    }
    wait_vm0_barrier();
    buf ^= 1;
  }
  // ---- merge parity partials (exact in fp32) ----
  float* pb = (float*)&lK[0][0][0] + qh * 1600;  // 64 lanes x 25 floats per qh
  if (p == 1) {
    float* dst = pb + lane * 25;
#pragma unroll
    for (int dt = 0; dt < 4; dt++)
#pragma unroll
      for (int r = 0; r < 4; r++) dst[dt * 4 + r] = o[dt][r];
#pragma unroll
    for (int r = 0; r < 4; r++) { dst[16 + r] = osum[r]; dst[20 + r] = m_[r]; }
  }
  __syncthreads();
  if (p == 0) {
    const float* src = pb + lane * 25;
#pragma unroll
    for (int r = 0; r < 4; r++) {
      float m1 = src[20 + r];
      float M = fmaxf(m_[r], m1);
      float s0 = exp2f(m_[r] - M);
      float s1 = exp2f(m1 - M);
      osum[r] = osum[r] * s0 + src[16 + r] * s1;
#pragma unroll
      for (int dt = 0; dt < 4; dt++)
        o[dt][r] = o[dt][r] * s0 + src[dt * 4 + r] * s1;
    }
#pragma unroll
    for (int dt = 0; dt < 4; dt++)
#pragma unroll
      for (int r = 0; r < 4; r++) {
        int row = q0 + lg * 4 + r;
        float val = o[dt][r] / osum[r];
        out[(size_t)(b * SEQ + row) * EMBED + h * HDIM + dt * 16 + lr] = f2bf(val);
      }
  }
}

extern "C" void kernel_launch(void* const* d_in, const int* in_sizes, int n_in,
                              void* d_out, int out_size, void* d_ws, size_t ws_size,
                              hipStream_t stream) {
  const float* x      = (const float*)d_in[0];
  const float* ln1_g  = (const float*)d_in[1];
  const float* ln1_b  = (const float*)d_in[2];
  const float* w_attn = (const float*)d_in[3];
  const float* b_attn = (const float*)d_in[4];
  const float* w_proj = (const float*)d_in[5];
  const float* b_proj = (const float*)d_in[6];
  const float* ln2_g  = (const float*)d_in[7];
  const float* ln2_b  = (const float*)d_in[8];
  const float* w_fc   = (const float*)d_in[9];
  const float* b_fc   = (const float*)d_in[10];
  const float* w_fc2  = (const float*)d_in[11];
  const float* b_fc2  = (const float*)d_in[12];
  float* outp = (float*)d_out;

  char* ws = (char*)d_ws;
  unsigned short* wT_attn = (unsigned short*)(ws);             // [3072][1024] bf16, 6 MB
  unsigned short* wT_proj = (unsigned short*)(ws + 6291456);   // [1024][1024] bf16, 2 MB
  unsigned short* wT_fc   = (unsigned short*)(ws + 8388608);   // [4096][1024] bf16, 8 MB
  unsigned short* wT_fc2  = (unsigned short*)(ws + 16777216);  // [1024][4096] bf16, 8 MB
  unsigned short* buf1    = (unsigned short*)(ws + 25165824);  // 8 MB: xln -> attnout -> x2ln
  float*          x1      = (float*)(ws + 33554432);           // 16 MB fp32 (written after attention)
  unsigned short* Vt      = (unsigned short*)(ws + 33554432);  // 8 MB bf16, dead once attention done
  unsigned short* qkv_h   = (unsigned short*)(ws + 50331648);  // 24 MB qkv -> 32 MB h (48..80 MB)

  dim3 blk(256);
  // all 4 weight transposes in one launch (12288 blocks)
  k_transpose_all<<<dim3(12288), blk, 0, stream>>>(
      w_attn, w_proj, w_fc, w_fc2, wT_attn, wT_proj, wT_fc, wT_fc2);
  // LN1: x -> xln (buf1)
  k_layernorm<<<dim3(MTOT), blk, 0, stream>>>(x, ln1_g, ln1_b, buf1);
  // QKV: 256^2 v3, 12x16 = 192 blocks
  k_gemm8<0><<<dim3(THREE_EMBED / 256, MTOT / 256), dim3(512), 0, stream>>>(
      buf1, wT_attn, b_attn, nullptr, nullptr, qkv_h, MTOT, THREE_EMBED, EMBED);
  // V transpose for attention
  k_transpose_v<<<dim3(SEQ / 32, 2 * BATCH * HEADS), blk, 0, stream>>>(qkv_h, Vt);
  // attention -> attnout (buf1): 64 q-tiles x 32 bh = 2048 blocks, KV-split
  k_attention<<<dim3(2048), blk, 0, stream>>>(qkv_h, Vt, buf1);
  // proj + residual: narrow BK=64, 16x32 = 512 blocks (overwrites Vt — dead)
  k_gemmN<1><<<dim3(EMBED / 64, MTOT / 128), blk, 0, stream>>>(
      buf1, wT_proj, b_proj, x, x1, nullptr, MTOT, EMBED, EMBED);
  // LN2: x1 -> x2ln (buf1)
  k_layernorm<<<dim3(MTOT), blk, 0, stream>>>(x1, ln2_g, ln2_b, buf1);
  // FC1 + GELU: 256^2 v3, 16x16 = 256 blocks
  k_gemm8<2><<<dim3(4 * EMBED / 256, MTOT / 256), dim3(512), 0, stream>>>(
      buf1, wT_fc, b_fc, nullptr, nullptr, qkv_h, MTOT, 4 * EMBED, EMBED);
  // FC2 + residual -> out: narrow BK=64, 512 blocks
  k_gemmN<1><<<dim3(EMBED / 64, MTOT / 128), blk, 0, stream>>>(
      qkv_h, wT_fc2, b_fc2, x1, outp, nullptr, MTOT, EMBED, 4 * EMBED);
}